// Round 5
// baseline (266.250 us; speedup 1.0000x reference)
//
#include <hip/hip_runtime.h>
#include <cstdint>
#include <cstddef>

// Problem constants (fixed by reference)
#define Bb   8
#define Ss   1024
#define NXx  1024
#define Hh   16
#define HDd  64
#define Mm   (Bb*Ss)      // 8192 rows

typedef __bf16 bf16x8 __attribute__((ext_vector_type(8)));
typedef float  f32x4  __attribute__((ext_vector_type(4)));

// cheap near-RNE fp32->bf16 (2 VALU ops); accuracy headroom is ~4x vs threshold
__device__ __forceinline__ unsigned short f2bf(float f) {
    union { float f; unsigned int u; } v; v.f = f;
    return (unsigned short)((v.u + 0x8000u) >> 16);
}

// async global->LDS, 16B per lane; LDS dest = wave-uniform base + lane*16
__device__ __forceinline__ void load_lds16(const unsigned short* g, unsigned short* lds_base) {
    __builtin_amdgcn_global_load_lds(
        (const __attribute__((address_space(1))) void*)g,
        (__attribute__((address_space(3))) void*)lds_base, 16, 0, 0);
}

// ---------------- merged prep: casts + weight transposes in one dispatch ----------------
__global__ __launch_bounds__(256) void prep(
    const float* __restrict__ x, const float* __restrict__ query,
    const float* __restrict__ caw, const float* __restrict__ cpw,
    unsigned short* __restrict__ xb, unsigned short* __restrict__ qb,
    unsigned short* __restrict__ Wt, unsigned short* __restrict__ Pt)
{
    __shared__ float tile[32][33];
    const int bid = blockIdx.x;
    const int tid = threadIdx.x;

    if (bid < 16384) {
        const float* in = (bid < 8192) ? x : query;
        unsigned short* out = (bid < 8192) ? xb : qb;
        const int i = ((bid & 8191) * 256 + tid) * 4;
        const float4 v = *(const float4*)(in + i);
        unsigned long long p = (unsigned long long)f2bf(v.x)
            | ((unsigned long long)f2bf(v.y) << 16)
            | ((unsigned long long)f2bf(v.z) << 32)
            | ((unsigned long long)f2bf(v.w) << 48);
        *(unsigned long long*)(out + i) = p;
        return;
    }

    const float* in;
    unsigned short* out;
    int C, t;
    if (bid < 16384 + 3072) { in = caw; out = Wt; C = 3072; t = bid - 16384; }
    else                    { in = cpw; out = Pt; C = 1024; t = bid - 19456; }
    const int ntx = C >> 5;
    const int c0 = (t % ntx) * 32, r0 = (t / ntx) * 32;
    const int tx = tid & 31, ty = tid >> 5;
    for (int i = ty; i < 32; i += 8)
        tile[i][tx] = in[(size_t)(r0 + i) * C + c0 + tx];
    __syncthreads();
    for (int i = ty; i < 32; i += 8)
        out[(size_t)(c0 + i) * 1024 + r0 + tx] = f2bf(tile[tx][i]);
}

// ---------------- 128x128-tile bf16 MFMA GEMM, BK=64 ----------------
// LDS [128][64] per matrix (128B rows = 32 banks). 3-bit XOR swizzle:
// phys_chunk = log_chunk ^ (row&7) -> per-16-lane phase each 4-bank group has
// 2 lanes = free. Staging source col = (lane&7)^(lane>>3) since row==lane>>3 mod 8.
// mode 0: QKV — A = (region==0 ? Aq : Ax); scatter to Qh/Kh head-major, Vt transposed.
// mode 1: proj — out_f fp32 [M][1024] + bias, direct coalesced stores.
__global__ __launch_bounds__(256) void gemm128(
    const unsigned short* __restrict__ Ax,
    const unsigned short* __restrict__ Aq,
    const unsigned short* __restrict__ Bt,
    const float* __restrict__ bias,
    int K, int mode,
    unsigned short* __restrict__ out_q,
    unsigned short* __restrict__ out_k,
    unsigned short* __restrict__ out_v,
    float* __restrict__ out_f)
{
    __shared__ unsigned short smem[16384];    // 32 KB staging; reused for epilogue bounce
    unsigned short (*As)[64] = (unsigned short (*)[64])(smem);
    unsigned short (*Bs)[64] = (unsigned short (*)[64])(smem + 8192);

    const int tid  = threadIdx.x;
    const int w    = tid >> 6;
    const int lane = tid & 63;

    // XCD-aware 2-D supertile swizzle: XCD (n&7) -> 16y x (nx/2)x block
    const int nx   = (mode == 0) ? 24 : 8;
    const int nxh  = nx >> 1;
    const int n    = blockIdx.x;
    const int xcd  = n & 7;
    const int sgrp = n >> 3;
    const int m0   = ((xcd >> 1) * 16 + sgrp / nxh) * 128;
    const int n0   = ((xcd & 1) * nxh + sgrp % nxh) * 128;
    const int region = n0 >> 10;
    const unsigned short* A = (mode == 0 && region == 0) ? Aq : Ax;

    const int wm   = (w >> 1) * 64;
    const int wn   = (w & 1) * 64;
    const int lrow = lane & 15;
    const int quad = lane >> 4;

    f32x4 acc[4][4] = {};

    // staging: wave w covers rows [w*32, w*32+32) in 4 calls of 8 rows each.
    const int rr   = lane >> 3;
    const int scol = (((lane & 7) ^ (lane >> 3)) << 3);
    const unsigned short* Ag = A  + (size_t)(m0 + w * 32 + rr) * K + scol;
    const unsigned short* Bg = Bt + (size_t)(n0 + w * 32 + rr) * K + scol;
    unsigned short* ldsA = smem + (w * 32) * 64;
    unsigned short* ldsB = smem + 8192 + (w * 32) * 64;

    const int swz = lrow & 7;                 // fragment-read swizzle

    for (int k0 = 0; k0 < K; k0 += 64) {
        __syncthreads();
#pragma unroll
        for (int c = 0; c < 4; ++c) {
            load_lds16(Ag + (size_t)(c * 8) * K + k0, ldsA + c * 512);
            load_lds16(Bg + (size_t)(c * 8) * K + k0, ldsB + c * 512);
        }
        __syncthreads();
#pragma unroll
        for (int kk = 0; kk < 2; ++kk) {
            bf16x8 af[4], bfr[4];
            const int pc = (((kk * 4 + quad) ^ swz) << 3);
#pragma unroll
            for (int i = 0; i < 4; ++i) {
                af[i]  = *(const bf16x8*)&As[wm + i * 16 + lrow][pc];
                bfr[i] = *(const bf16x8*)&Bs[wn + i * 16 + lrow][pc];
            }
#pragma unroll
            for (int i = 0; i < 4; ++i)
#pragma unroll
                for (int j = 0; j < 4; ++j)
                    acc[i][j] = __builtin_amdgcn_mfma_f32_16x16x32_bf16(af[i], bfr[j], acc[i][j], 0, 0, 0);
        }
    }

    __syncthreads();   // all waves done reading As/Bs; safe to reuse smem

    if (mode == 1) {
#pragma unroll
        for (int i = 0; i < 4; ++i)
#pragma unroll
            for (int j = 0; j < 4; ++j) {
                const int ncol = n0 + wn + j * 16 + lrow;
                const float bv = bias[ncol];
#pragma unroll
                for (int r = 0; r < 4; ++r) {
                    const int mrow = m0 + wm + i * 16 + quad * 4 + r;
                    out_f[(size_t)mrow * NXx + ncol] = acc[i][j][r] + bv;
                }
            }
        return;
    }

    unsigned short* ep = smem + w * 2048;     // per-wave 4 KB bounce region

    if (region != 2) {
        unsigned short* outp = (region == 0) ? out_q : out_k;
#pragma unroll
        for (int j = 0; j < 4; ++j) {
            const float bv = bias[n0 + wn + j * 16 + lrow];
#pragma unroll
            for (int i = 0; i < 4; ++i)
#pragma unroll
                for (int r = 0; r < 4; ++r)
                    ep[(i * 16 + quad * 4 + r) * 24 + lrow] = f2bf(acc[i][j][r] + bv);
            // per-wave region: in-wave LDS ordering, no barrier needed
#pragma unroll
            for (int t = 0; t < 2; ++t) {
                const int c    = t * 64 + lane;
                const int row  = c >> 1, ch = (c & 1) * 8;
                const int mrow = m0 + wm + row;
                const int cc   = (n0 + wn + j * 16 + ch) & (NXx - 1);
                const int hh   = cc >> 6, dd = cc & 63;
                const int bh   = (mrow >> 10) * Hh + hh;
                const int ss   = mrow & (Ss - 1);
                *(uint4*)&outp[((size_t)bh * Ss + ss) * HDd + dd] =
                    *(const uint4*)&ep[row * 24 + ch];
            }
        }
    } else {
        // V: bounce transposed [col][row] (stride 72) for contiguous-s wide stores
#pragma unroll
        for (int j = 0; j < 4; ++j) {
            const float bv = bias[n0 + wn + j * 16 + lrow];
#pragma unroll
            for (int i = 0; i < 4; ++i)
#pragma unroll
                for (int r = 0; r < 4; ++r)
                    ep[lrow * 72 + i * 16 + quad * 4 + r] = f2bf(acc[i][j][r] + bv);
#pragma unroll
            for (int t = 0; t < 2; ++t) {
                const int c    = t * 64 + lane;
                const int col  = c >> 3, rc = (c & 7) * 8;
                const int cc   = (n0 + wn + j * 16 + col) & (NXx - 1);
                const int hh   = cc >> 6, dd = cc & 63;
                const int mrow = m0 + wm + rc;
                const int bh   = (mrow >> 10) * Hh + hh;
                const int ss   = mrow & (Ss - 1);
                *(uint4*)&out_v[((size_t)bh * HDd + dd) * Ss + ss] =
                    *(const uint4*)&ep[col * 72 + rc];
            }
        }
    }
}

// ---------------- flash-style causal attention, 128-row q-supertiles ----------------
// Qh,Kh: [BH][S][64] bf16; Vt: [BH][64][S] bf16; about: [B][S][H*64] bf16.
// blockIdx = pr*128 + bh (pr in 0..3). Block does q-supertiles pr and 7-pr
// (128 rows each; wave w owns 32 rows) -> uniform 18 k-iterations of 64 keys.
// Fully-masked waves skip compute (wave-uniform branch). 2 barriers/iter.
__global__ __launch_bounds__(256) void flash_attn(
    const unsigned short* __restrict__ Qh,
    const unsigned short* __restrict__ Kh,
    const unsigned short* __restrict__ Vt,
    unsigned short* __restrict__ about)
{
    __shared__ unsigned short Ks[64][64];     // phys_chunk = log ^ (row&7)
    __shared__ unsigned short Vs[64][64];
    __shared__ unsigned short Pl[4][32][72];  // per-wave P tile (stride 144B, 2-way)

    const int tid  = threadIdx.x;
    const int w    = tid >> 6;
    const int lane = tid & 63;
    const int bh   = blockIdx.x & 127;
    const int pr   = blockIdx.x >> 7;
    const int b    = bh >> 4, h = bh & 15;
    const int lrow = lane & 15;
    const int quad = lane >> 4;

    const unsigned short* Qb = Qh + (size_t)bh * Ss * HDd;
    const unsigned short* Kb = Kh + (size_t)bh * Ss * HDd;
    const unsigned short* Vb = Vt + (size_t)bh * HDd * Ss;

    // staging: 2 calls of 8 rows per matrix per wave; source col permuted
    const int sr = lane >> 3;
    const int lc = (((lane & 7) ^ (lane >> 3)) << 3);
    unsigned short* ldsK0 = &Ks[w * 16][0];
    unsigned short* ldsK1 = &Ks[w * 16 + 8][0];
    unsigned short* ldsV0 = &Vs[w * 16][0];
    unsigned short* ldsV1 = &Vs[w * 16 + 8][0];

    const int swz = lrow & 7;
    const int ca = ((quad ^ swz) << 3);            // k/d 0..31
    const int cb = (((4 + quad) ^ swz) << 3);      // k/d 32..63

    for (int half = 0; half < 2; ++half) {
        const int qt = half ? (7 - pr) : pr;
        const int qw = qt * 128 + w * 32;          // wave's first q row

        bf16x8 aq[2][2];
#pragma unroll
        for (int g = 0; g < 2; ++g)
#pragma unroll
            for (int c = 0; c < 2; ++c)
                aq[g][c] = *(const bf16x8*)(Qb + (size_t)(qw + g * 16 + lrow) * HDd + c * 32 + quad * 8);

        f32x4 O[2][4] = {};
        float lsum[2][4] = {};

        const int nkt = 2 * qt + 2;                // block-uniform
        for (int kt = 0; kt < nkt; ++kt) {
            const int k0 = kt * 64;

            __syncthreads();   // prior iter done reading Ks/Vs
            load_lds16(Kb + (size_t)(k0 + w * 16 + sr) * HDd + lc,     ldsK0);
            load_lds16(Kb + (size_t)(k0 + w * 16 + sr + 8) * HDd + lc, ldsK1);
            load_lds16(Vb + (size_t)(w * 16 + sr) * Ss + k0 + lc,      ldsV0);
            load_lds16(Vb + (size_t)(w * 16 + sr + 8) * Ss + k0 + lc,  ldsV1);
            __syncthreads();

            if (k0 > qw + 31) continue;            // fully masked (wave-uniform)

            // QK^T: 32 q-rows x 64 keys
            f32x4 s[2][4] = {};
#pragma unroll
            for (int j = 0; j < 4; ++j) {
                const bf16x8 b0 = *(const bf16x8*)&Ks[j * 16 + lrow][ca];
                const bf16x8 b1 = *(const bf16x8*)&Ks[j * 16 + lrow][cb];
                s[0][j] = __builtin_amdgcn_mfma_f32_16x16x32_bf16(aq[0][0], b0, s[0][j], 0, 0, 0);
                s[0][j] = __builtin_amdgcn_mfma_f32_16x16x32_bf16(aq[0][1], b1, s[0][j], 0, 0, 0);
                s[1][j] = __builtin_amdgcn_mfma_f32_16x16x32_bf16(aq[1][0], b0, s[1][j], 0, 0, 0);
                s[1][j] = __builtin_amdgcn_mfma_f32_16x16x32_bf16(aq[1][1], b1, s[1][j], 0, 0, 0);
            }

            const bool needMask = (k0 + 63 > qw);  // wave-uniform
#pragma unroll
            for (int g = 0; g < 2; ++g)
#pragma unroll
                for (int r = 0; r < 4; ++r) {
                    const int q = qw + g * 16 + quad * 4 + r;
#pragma unroll
                    for (int j = 0; j < 4; ++j) {
                        float e = __expf(s[g][j][r] * 0.125f);
                        if (needMask && (k0 + j * 16 + lrow > q)) e = 0.f;
                        lsum[g][r] += e;
                        Pl[w][g * 16 + quad * 4 + r][j * 16 + lrow] = f2bf(e);
                    }
                }
            // Pl[w] is per-wave: in-wave lgkmcnt ordering suffices, no barrier

            bf16x8 ap[2][2];
#pragma unroll
            for (int g = 0; g < 2; ++g)
#pragma unroll
                for (int c = 0; c < 2; ++c)
                    ap[g][c] = *(const bf16x8*)&Pl[w][g * 16 + lrow][c * 32 + quad * 8];
#pragma unroll
            for (int f = 0; f < 4; ++f) {
                const bf16x8 bv0 = *(const bf16x8*)&Vs[f * 16 + lrow][ca];
                const bf16x8 bv1 = *(const bf16x8*)&Vs[f * 16 + lrow][cb];
                O[0][f] = __builtin_amdgcn_mfma_f32_16x16x32_bf16(ap[0][0], bv0, O[0][f], 0, 0, 0);
                O[0][f] = __builtin_amdgcn_mfma_f32_16x16x32_bf16(ap[0][1], bv1, O[0][f], 0, 0, 0);
                O[1][f] = __builtin_amdgcn_mfma_f32_16x16x32_bf16(ap[1][0], bv0, O[1][f], 0, 0, 0);
                O[1][f] = __builtin_amdgcn_mfma_f32_16x16x32_bf16(ap[1][1], bv1, O[1][f], 0, 0, 0);
            }
        }

        // epilogue: reduce l across the 16 score lanes, normalize, store
#pragma unroll
        for (int g = 0; g < 2; ++g)
#pragma unroll
            for (int r = 0; r < 4; ++r) {
                float l = lsum[g][r];
                l += __shfl_xor(l, 1);
                l += __shfl_xor(l, 2);
                l += __shfl_xor(l, 4);
                l += __shfl_xor(l, 8);
                const float inv = 1.0f / l;
                const int q = qw + g * 16 + quad * 4 + r;
                const size_t base = ((size_t)b * Ss + q) * NXx + h * HDd;
#pragma unroll
                for (int f = 0; f < 4; ++f)
                    about[base + f * 16 + lrow] = f2bf(O[g][f][r] * inv);
            }
    }
}

// ---------------- launch ----------------
extern "C" void kernel_launch(void* const* d_in, const int* in_sizes, int n_in,
                              void* d_out, int out_size, void* d_ws, size_t ws_size,
                              hipStream_t stream) {
    const float* x        = (const float*)d_in[0];
    const float* query    = (const float*)d_in[1];
    const float* c_attn_w = (const float*)d_in[2];
    const float* c_attn_b = (const float*)d_in[3];
    const float* c_proj_w = (const float*)d_in[4];
    const float* c_proj_b = (const float*)d_in[5];
    float* out = (float*)d_out;

    const size_t nTok = (size_t)Mm * NXx;          // 8388608
    char* ws = (char*)d_ws;
    unsigned short* xb    = (unsigned short*)ws;                 ws += nTok * 2;
    unsigned short* qb    = (unsigned short*)ws;                 ws += nTok * 2;
    unsigned short* Wt    = (unsigned short*)ws;                 ws += (size_t)3 * NXx * NXx * 2;  // [3072][1024]
    unsigned short* Pt    = (unsigned short*)ws;                 ws += (size_t)NXx * NXx * 2;      // [1024][1024]
    unsigned short* Qh    = (unsigned short*)ws;                 ws += nTok * 2;
    unsigned short* Kh    = (unsigned short*)ws;                 ws += nTok * 2;
    unsigned short* Vt    = (unsigned short*)ws;                 ws += nTok * 2;
    unsigned short* about = (unsigned short*)ws;                 ws += nTok * 2;
    if ((size_t)(ws - (char*)d_ws) > ws_size) return;

    // merged prep: casts + transposes
    prep<<<20480, 256, 0, stream>>>(x, query, c_attn_w, c_proj_w, xb, qb, Wt, Pt);

    // QKV: M=8192, N=3072, K=1024
    gemm128<<<dim3(24 * 64), 256, 0, stream>>>(xb, qb, Wt, c_attn_b, NXx, 0,
                                               Qh, Kh, Vt, nullptr);
    // causal flash attention (128-row supertile pairs)
    flash_attn<<<512, 256, 0, stream>>>(Qh, Kh, Vt, about);

    // output projection: M=8192, N=1024, K=1024 -> fp32 out
    gemm128<<<dim3(8 * 64), 256, 0, stream>>>(about, nullptr, Pt, c_proj_b, NXx, 1,
                                              nullptr, nullptr, nullptr, out);
}

// Round 6
// 262.031 us; speedup vs baseline: 1.0161x; 1.0161x over previous
//
#include <hip/hip_runtime.h>
#include <cstdint>
#include <cstddef>

// Problem constants (fixed by reference)
#define Bb   8
#define Ss   1024
#define NXx  1024
#define Hh   16
#define HDd  64
#define Mm   (Bb*Ss)      // 8192 rows

typedef __bf16 bf16x8 __attribute__((ext_vector_type(8)));
typedef float  f32x4  __attribute__((ext_vector_type(4)));

// cheap near-RNE fp32->bf16 (2 VALU ops); accuracy headroom is ~4x vs threshold
__device__ __forceinline__ unsigned short f2bf(float f) {
    union { float f; unsigned int u; } v; v.f = f;
    return (unsigned short)((v.u + 0x8000u) >> 16);
}
__device__ __forceinline__ unsigned int f2bf_hi(float f) {   // bf16 in high half
    union { float f; unsigned int u; } v; v.f = f;
    return (v.u + 0x8000u) & 0xffff0000u;
}

// async global->LDS, 16B per lane; LDS dest = wave-uniform base + lane*16
__device__ __forceinline__ void load_lds16(const unsigned short* g, unsigned short* lds_base) {
    __builtin_amdgcn_global_load_lds(
        (const __attribute__((address_space(1))) void*)g,
        (__attribute__((address_space(3))) void*)lds_base, 16, 0, 0);
}

// ---------------- merged prep: casts + weight transposes in one dispatch ----------------
__global__ __launch_bounds__(256) void prep(
    const float* __restrict__ x, const float* __restrict__ query,
    const float* __restrict__ caw, const float* __restrict__ cpw,
    unsigned short* __restrict__ xb, unsigned short* __restrict__ qb,
    unsigned short* __restrict__ Wt, unsigned short* __restrict__ Pt)
{
    __shared__ float tile[32][33];
    const int bid = blockIdx.x;
    const int tid = threadIdx.x;

    if (bid < 16384) {
        const float* in = (bid < 8192) ? x : query;
        unsigned short* out = (bid < 8192) ? xb : qb;
        const int i = ((bid & 8191) * 256 + tid) * 4;
        const float4 v = *(const float4*)(in + i);
        unsigned long long p = (unsigned long long)f2bf(v.x)
            | ((unsigned long long)f2bf(v.y) << 16)
            | ((unsigned long long)f2bf(v.z) << 32)
            | ((unsigned long long)f2bf(v.w) << 48);
        *(unsigned long long*)(out + i) = p;
        return;
    }

    const float* in;
    unsigned short* out;
    int C, t;
    if (bid < 16384 + 3072) { in = caw; out = Wt; C = 3072; t = bid - 16384; }
    else                    { in = cpw; out = Pt; C = 1024; t = bid - 19456; }
    const int ntx = C >> 5;
    const int c0 = (t % ntx) * 32, r0 = (t / ntx) * 32;
    const int tx = tid & 31, ty = tid >> 5;
    for (int i = ty; i < 32; i += 8)
        tile[i][tx] = in[(size_t)(r0 + i) * C + c0 + tx];
    __syncthreads();
    for (int i = ty; i < 32; i += 8)
        out[(size_t)(c0 + i) * 1024 + r0 + tx] = f2bf(tile[tx][i]);
}

// ---------------- 128x128-tile bf16 MFMA GEMM, BK=64 ----------------
// LDS [128][64] per matrix (128B rows = 32 banks). 3-bit XOR swizzle:
// phys_chunk = log_chunk ^ (row&7) -> 2 lanes per 4-bank group = free.
// mode 0: QKV — A = (region==0 ? Aq : Ax); scatter to Qh/Kh head-major, Vt transposed.
// mode 1: proj — out_f fp32 [M][1024] + bias, direct coalesced stores.
__global__ __launch_bounds__(256) void gemm128(
    const unsigned short* __restrict__ Ax,
    const unsigned short* __restrict__ Aq,
    const unsigned short* __restrict__ Bt,
    const float* __restrict__ bias,
    int K, int mode,
    unsigned short* __restrict__ out_q,
    unsigned short* __restrict__ out_k,
    unsigned short* __restrict__ out_v,
    float* __restrict__ out_f)
{
    __shared__ unsigned short smem[16384];    // 32 KB staging; reused for epilogue bounce
    unsigned short (*As)[64] = (unsigned short (*)[64])(smem);
    unsigned short (*Bs)[64] = (unsigned short (*)[64])(smem + 8192);

    const int tid  = threadIdx.x;
    const int w    = tid >> 6;
    const int lane = tid & 63;

    // XCD-aware 2-D supertile swizzle: XCD (n&7) -> 16y x (nx/2)x block
    const int nx   = (mode == 0) ? 24 : 8;
    const int nxh  = nx >> 1;
    const int n    = blockIdx.x;
    const int xcd  = n & 7;
    const int sgrp = n >> 3;
    const int m0   = ((xcd >> 1) * 16 + sgrp / nxh) * 128;
    const int n0   = ((xcd & 1) * nxh + sgrp % nxh) * 128;
    const int region = n0 >> 10;
    const unsigned short* A = (mode == 0 && region == 0) ? Aq : Ax;

    const int wm   = (w >> 1) * 64;
    const int wn   = (w & 1) * 64;
    const int lrow = lane & 15;
    const int quad = lane >> 4;

    f32x4 acc[4][4] = {};

    // staging: wave w covers rows [w*32, w*32+32) in 4 calls of 8 rows each.
    const int rr   = lane >> 3;
    const int scol = (((lane & 7) ^ (lane >> 3)) << 3);
    const unsigned short* Ag = A  + (size_t)(m0 + w * 32 + rr) * K + scol;
    const unsigned short* Bg = Bt + (size_t)(n0 + w * 32 + rr) * K + scol;
    unsigned short* ldsA = smem + (w * 32) * 64;
    unsigned short* ldsB = smem + 8192 + (w * 32) * 64;

    const int swz = lrow & 7;                 // fragment-read swizzle

    for (int k0 = 0; k0 < K; k0 += 64) {
        __syncthreads();
#pragma unroll
        for (int c = 0; c < 4; ++c) {
            load_lds16(Ag + (size_t)(c * 8) * K + k0, ldsA + c * 512);
            load_lds16(Bg + (size_t)(c * 8) * K + k0, ldsB + c * 512);
        }
        __syncthreads();
#pragma unroll
        for (int kk = 0; kk < 2; ++kk) {
            bf16x8 af[4], bfr[4];
            const int pc = (((kk * 4 + quad) ^ swz) << 3);
#pragma unroll
            for (int i = 0; i < 4; ++i) {
                af[i]  = *(const bf16x8*)&As[wm + i * 16 + lrow][pc];
                bfr[i] = *(const bf16x8*)&Bs[wn + i * 16 + lrow][pc];
            }
#pragma unroll
            for (int i = 0; i < 4; ++i)
#pragma unroll
                for (int j = 0; j < 4; ++j)
                    acc[i][j] = __builtin_amdgcn_mfma_f32_16x16x32_bf16(af[i], bfr[j], acc[i][j], 0, 0, 0);
        }
    }

    __syncthreads();   // all waves done reading As/Bs; safe to reuse smem

    if (mode == 1) {
#pragma unroll
        for (int i = 0; i < 4; ++i)
#pragma unroll
            for (int j = 0; j < 4; ++j) {
                const int ncol = n0 + wn + j * 16 + lrow;
                const float bv = bias[ncol];
#pragma unroll
                for (int r = 0; r < 4; ++r) {
                    const int mrow = m0 + wm + i * 16 + quad * 4 + r;
                    out_f[(size_t)mrow * NXx + ncol] = acc[i][j][r] + bv;
                }
            }
        return;
    }

    unsigned short* ep = smem + w * 2048;     // per-wave 4 KB bounce region

    if (region != 2) {
        unsigned short* outp = (region == 0) ? out_q : out_k;
#pragma unroll
        for (int j = 0; j < 4; ++j) {
            const float bv = bias[n0 + wn + j * 16 + lrow];
#pragma unroll
            for (int i = 0; i < 4; ++i)
#pragma unroll
                for (int r = 0; r < 4; ++r)
                    ep[(i * 16 + quad * 4 + r) * 24 + lrow] = f2bf(acc[i][j][r] + bv);
            // per-wave region: in-wave LDS ordering, no barrier needed
#pragma unroll
            for (int t = 0; t < 2; ++t) {
                const int c    = t * 64 + lane;
                const int row  = c >> 1, ch = (c & 1) * 8;
                const int mrow = m0 + wm + row;
                const int cc   = (n0 + wn + j * 16 + ch) & (NXx - 1);
                const int hh   = cc >> 6, dd = cc & 63;
                const int bh   = (mrow >> 10) * Hh + hh;
                const int ss   = mrow & (Ss - 1);
                *(uint4*)&outp[((size_t)bh * Ss + ss) * HDd + dd] =
                    *(const uint4*)&ep[row * 24 + ch];
            }
        }
    } else {
        // V: bounce transposed [col][row] (stride 72) for contiguous-s wide stores
#pragma unroll
        for (int j = 0; j < 4; ++j) {
            const float bv = bias[n0 + wn + j * 16 + lrow];
#pragma unroll
            for (int i = 0; i < 4; ++i)
#pragma unroll
                for (int r = 0; r < 4; ++r)
                    ep[lrow * 72 + i * 16 + quad * 4 + r] = f2bf(acc[i][j][r] + bv);
#pragma unroll
            for (int t = 0; t < 2; ++t) {
                const int c    = t * 64 + lane;
                const int col  = c >> 3, rc = (c & 7) * 8;
                const int cc   = (n0 + wn + j * 16 + col) & (NXx - 1);
                const int hh   = cc >> 6, dd = cc & 63;
                const int mrow = m0 + wm + rc;
                const int bh   = (mrow >> 10) * Hh + hh;
                const int ss   = mrow & (Ss - 1);
                *(uint4*)&out_v[((size_t)bh * HDd + dd) * Ss + ss] =
                    *(const uint4*)&ep[col * 72 + rc];
            }
        }
    }
}

// ---------------- flash-style causal attention, S^T formulation ----------------
// Qh,Kh: [BH][S][64] bf16; Vt: [BH][64][S] bf16; about: [B][S][H*64] bf16.
// blockIdx = pr*128 + bh (pr 0..3); block does q-supertiles pr and 7-pr (128 rows,
// wave w owns 32) -> uniform 18 k-iterations of 64 keys. QK^T computed TRANSPOSED
// (A=K-frag, B=Q-frag -> D[key][q]): each lane's 4 acc elements = 4 consecutive
// keys for fixed q, so P stores to Pl[q][key] as ONE packed b64 per (g,j) —
// 8 b64 writes replace 32 scalar b16 writes. PV reads P as A-op (contiguous b128)
// vs Vs[d][key] as B-op. l: per-lane partial (q=lrow), quad-reduce at end.
__global__ __launch_bounds__(256) void flash_attn(
    const unsigned short* __restrict__ Qh,
    const unsigned short* __restrict__ Kh,
    const unsigned short* __restrict__ Vt,
    unsigned short* __restrict__ about)
{
    __shared__ unsigned short Ks[64][64];     // phys_chunk = log ^ (row&7)
    __shared__ unsigned short Vs[64][64];
    __shared__ unsigned short Pl[4][32][72];  // per-wave P, [q][key], stride 144B

    const int tid  = threadIdx.x;
    const int w    = tid >> 6;
    const int lane = tid & 63;
    const int bh   = blockIdx.x & 127;
    const int pr   = blockIdx.x >> 7;
    const int b    = bh >> 4, h = bh & 15;
    const int lrow = lane & 15;
    const int quad = lane >> 4;

    const unsigned short* Qb = Qh + (size_t)bh * Ss * HDd;
    const unsigned short* Kb = Kh + (size_t)bh * Ss * HDd;
    const unsigned short* Vb = Vt + (size_t)bh * HDd * Ss;

    // staging: 2 calls of 8 rows per matrix per wave; source col permuted
    const int sr = lane >> 3;
    const int lc = (((lane & 7) ^ (lane >> 3)) << 3);
    unsigned short* ldsK0 = &Ks[w * 16][0];
    unsigned short* ldsK1 = &Ks[w * 16 + 8][0];
    unsigned short* ldsV0 = &Vs[w * 16][0];
    unsigned short* ldsV1 = &Vs[w * 16 + 8][0];

    const int swz = lrow & 7;
    const int ca = ((quad ^ swz) << 3);            // k/d 0..31
    const int cb = (((4 + quad) ^ swz) << 3);      // k/d 32..63

    for (int half = 0; half < 2; ++half) {
        const int qt = half ? (7 - pr) : pr;
        const int qw = qt * 128 + w * 32;          // wave's first q row

        bf16x8 aq[2][2];
#pragma unroll
        for (int g = 0; g < 2; ++g)
#pragma unroll
            for (int c = 0; c < 2; ++c)
                aq[g][c] = *(const bf16x8*)(Qb + (size_t)(qw + g * 16 + lrow) * HDd + c * 32 + quad * 8);

        f32x4 O[2][4] = {};
        float lsum[2] = { 0.f, 0.f };              // per-lane partial, q = qw+g*16+lrow

        const int nkt = 2 * qt + 2;                // block-uniform
        for (int kt = 0; kt < nkt; ++kt) {
            const int k0 = kt * 64;

            __syncthreads();   // prior iter done reading Ks/Vs
            load_lds16(Kb + (size_t)(k0 + w * 16 + sr) * HDd + lc,     ldsK0);
            load_lds16(Kb + (size_t)(k0 + w * 16 + sr + 8) * HDd + lc, ldsK1);
            load_lds16(Vb + (size_t)(w * 16 + sr) * Ss + k0 + lc,      ldsV0);
            load_lds16(Vb + (size_t)(w * 16 + sr + 8) * Ss + k0 + lc,  ldsV1);
            __syncthreads();

            if (k0 > qw + 31) continue;            // fully masked (wave-uniform)

            // S^T = K·Q^T: D[key = j*16+quad*4+r][q = g*16+lrow]
            f32x4 st[2][4] = {};
#pragma unroll
            for (int j = 0; j < 4; ++j) {
                const bf16x8 kf0 = *(const bf16x8*)&Ks[j * 16 + lrow][ca];
                const bf16x8 kf1 = *(const bf16x8*)&Ks[j * 16 + lrow][cb];
                st[0][j] = __builtin_amdgcn_mfma_f32_16x16x32_bf16(kf0, aq[0][0], st[0][j], 0, 0, 0);
                st[0][j] = __builtin_amdgcn_mfma_f32_16x16x32_bf16(kf1, aq[0][1], st[0][j], 0, 0, 0);
                st[1][j] = __builtin_amdgcn_mfma_f32_16x16x32_bf16(kf0, aq[1][0], st[1][j], 0, 0, 0);
                st[1][j] = __builtin_amdgcn_mfma_f32_16x16x32_bf16(kf1, aq[1][1], st[1][j], 0, 0, 0);
            }

            const bool needMask = (k0 + 63 > qw);  // wave-uniform
#pragma unroll
            for (int g = 0; g < 2; ++g) {
                const int qg = qw + g * 16 + lrow;  // this lane's q row
#pragma unroll
                for (int j = 0; j < 4; ++j) {
                    const int kbase = k0 + j * 16 + quad * 4;
                    float e0 = __expf(st[g][j][0] * 0.125f);
                    float e1 = __expf(st[g][j][1] * 0.125f);
                    float e2 = __expf(st[g][j][2] * 0.125f);
                    float e3 = __expf(st[g][j][3] * 0.125f);
                    if (needMask) {
                        if (kbase     > qg) e0 = 0.f;
                        if (kbase + 1 > qg) e1 = 0.f;
                        if (kbase + 2 > qg) e2 = 0.f;
                        if (kbase + 3 > qg) e3 = 0.f;
                    }
                    lsum[g] += (e0 + e1) + (e2 + e3);
                    uint2 pk;
                    pk.x = (unsigned)f2bf(e0) | f2bf_hi(e1);
                    pk.y = (unsigned)f2bf(e2) | f2bf_hi(e3);
                    *(uint2*)&Pl[w][g * 16 + lrow][j * 16 + quad * 4] = pk;
                }
            }
            // Pl[w] is per-wave: in-wave DS ordering suffices, no barrier

            bf16x8 ap[2][2];
#pragma unroll
            for (int g = 0; g < 2; ++g)
#pragma unroll
                for (int c = 0; c < 2; ++c)
                    ap[g][c] = *(const bf16x8*)&Pl[w][g * 16 + lrow][c * 32 + quad * 8];
#pragma unroll
            for (int f = 0; f < 4; ++f) {
                const bf16x8 vf0 = *(const bf16x8*)&Vs[f * 16 + lrow][ca];
                const bf16x8 vf1 = *(const bf16x8*)&Vs[f * 16 + lrow][cb];
                O[0][f] = __builtin_amdgcn_mfma_f32_16x16x32_bf16(ap[0][0], vf0, O[0][f], 0, 0, 0);
                O[0][f] = __builtin_amdgcn_mfma_f32_16x16x32_bf16(ap[0][1], vf1, O[0][f], 0, 0, 0);
                O[1][f] = __builtin_amdgcn_mfma_f32_16x16x32_bf16(ap[1][0], vf0, O[1][f], 0, 0, 0);
                O[1][f] = __builtin_amdgcn_mfma_f32_16x16x32_bf16(ap[1][1], vf1, O[1][f], 0, 0, 0);
            }
        }

        // epilogue: full l for q=qw+g*16+lrow lives in this lane's column; reduce
        // over the 4 quads, then broadcast to the lanes that hold O rows.
#pragma unroll
        for (int g = 0; g < 2; ++g) {
            float l = lsum[g];
            l += __shfl_xor(l, 16);
            l += __shfl_xor(l, 32);
            const float inv = 1.0f / l;
#pragma unroll
            for (int r = 0; r < 4; ++r) {
                const float invr = __shfl(inv, quad * 4 + r);   // lane with lrow==quad*4+r
                const int q = qw + g * 16 + quad * 4 + r;
                const size_t base = ((size_t)b * Ss + q) * NXx + h * HDd;
#pragma unroll
                for (int f = 0; f < 4; ++f)
                    about[base + f * 16 + lrow] = f2bf(O[g][f][r] * invr);
            }
        }
    }
}

// ---------------- launch ----------------
extern "C" void kernel_launch(void* const* d_in, const int* in_sizes, int n_in,
                              void* d_out, int out_size, void* d_ws, size_t ws_size,
                              hipStream_t stream) {
    const float* x        = (const float*)d_in[0];
    const float* query    = (const float*)d_in[1];
    const float* c_attn_w = (const float*)d_in[2];
    const float* c_attn_b = (const float*)d_in[3];
    const float* c_proj_w = (const float*)d_in[4];
    const float* c_proj_b = (const float*)d_in[5];
    float* out = (float*)d_out;

    const size_t nTok = (size_t)Mm * NXx;          // 8388608
    char* ws = (char*)d_ws;
    unsigned short* xb    = (unsigned short*)ws;                 ws += nTok * 2;
    unsigned short* qb    = (unsigned short*)ws;                 ws += nTok * 2;
    unsigned short* Wt    = (unsigned short*)ws;                 ws += (size_t)3 * NXx * NXx * 2;  // [3072][1024]
    unsigned short* Pt    = (unsigned short*)ws;                 ws += (size_t)NXx * NXx * 2;      // [1024][1024]
    unsigned short* Qh    = (unsigned short*)ws;                 ws += nTok * 2;
    unsigned short* Kh    = (unsigned short*)ws;                 ws += nTok * 2;
    unsigned short* Vt    = (unsigned short*)ws;                 ws += nTok * 2;
    unsigned short* about = (unsigned short*)ws;                 ws += nTok * 2;
    if ((size_t)(ws - (char*)d_ws) > ws_size) return;

    // merged prep: casts + transposes
    prep<<<20480, 256, 0, stream>>>(x, query, c_attn_w, c_proj_w, xb, qb, Wt, Pt);

    // QKV: M=8192, N=3072, K=1024
    gemm128<<<dim3(24 * 64), 256, 0, stream>>>(xb, qb, Wt, c_attn_b, NXx, 0,
                                               Qh, Kh, Vt, nullptr);
    // causal flash attention (S^T formulation, 128-row supertile pairs)
    flash_attn<<<512, 256, 0, stream>>>(Qh, Kh, Vt, about);

    // output projection: M=8192, N=1024, K=1024 -> fp32 out
    gemm128<<<dim3(8 * 64), 256, 0, stream>>>(about, nullptr, Pt, c_proj_b, NXx, 1,
                                              nullptr, nullptr, nullptr, out);
}